// Round 3
// baseline (196.850 us; speedup 1.0000x reference)
//
#include <hip/hip_runtime.h>
#include <math.h>

// Tropical (max-plus) depthwise 3x3 conv, stride=1, pad=1, dil=1.
// x: (8,64,224,224) fp32; kernel: (64,1,3,3) fp32; out same shape.
// R2 design: one thread -> 16-output-row x float4 column strip with a rolling
// 3-row register window. Per output row: 1 float4 + 2 halo scalar loads
// (issued one iteration ahead -> distance-1 prefetch), 1 float4 store.
// Address math amortized via full unroll; nested fmax triples -> v_max3_f32.

#define H_DIM 224
#define W_DIM 224
#define W4 56            // W/4
#define STRIP 16         // output rows per thread
#define GS (H_DIM / STRIP)   // 14 strips per plane
#define C_DIM 64
#define NEG (-INFINITY)

struct Row { float4 v; float l, r; };

__device__ __forceinline__ Row load_row(const float* __restrict__ plane, int r,
                                        int j0, bool has_l, bool has_r) {
    Row o;
    if (r >= 0 && r < H_DIM) {
        const float* row = plane + r * W_DIM;
        o.v = *(const float4*)(row + j0);
        o.l = has_l ? row[j0 - 1] : NEG;
        o.r = has_r ? row[j0 + 4] : NEG;
    } else {
        o.v = make_float4(NEG, NEG, NEG, NEG);
        o.l = NEG;
        o.r = NEG;
    }
    return o;
}

__device__ __forceinline__ float m3(float a, float b, float c) {
    return fmaxf(fmaxf(a, b), c);   // -> v_max3_f32
}

__global__ __launch_bounds__(256) void tropical_conv_kernel(
    const float* __restrict__ x,
    const float* __restrict__ kern,
    float* __restrict__ out,
    int total)   // total threads = B*C*GS*W4
{
    int idx = blockIdx.x * blockDim.x + threadIdx.x;
    if (idx >= total) return;

    int j4 = idx % W4;
    int t  = idx / W4;
    int g  = t % GS;
    int bc = t / GS;
    int c  = bc & (C_DIM - 1);

    const float* kc = kern + c * 9;
    float k00 = kc[0], k01 = kc[1], k02 = kc[2];
    float k10 = kc[3], k11 = kc[4], k12 = kc[5];
    float k20 = kc[6], k21 = kc[7], k22 = kc[8];

    const float* plane  = x   + (size_t)bc * (H_DIM * W_DIM);
    float*       oplane = out + (size_t)bc * (H_DIM * W_DIM);
    int j0 = j4 * 4;
    int i0 = g * STRIP;
    bool has_l = (j4 > 0);
    bool has_r = (j4 < W4 - 1);

    // Rolling window: A = row i-1, B = row i, C = row i+1 for output row i.
    Row A = load_row(plane, i0 - 1, j0, has_l, has_r);
    Row B = load_row(plane, i0,     j0, has_l, has_r);
    Row C = load_row(plane, i0 + 1, j0, has_l, has_r);

    #pragma unroll
    for (int o = 0; o < STRIP; ++o) {
        // Prefetch row i+2 before computing output row i (distance-1).
        Row N = load_row(plane, i0 + o + 2, j0, has_l, has_r);

        float4 acc;
        acc.x = m3(m3(A.l   + k00, A.v.x + k01, A.v.y + k02),
                   m3(B.l   + k10, B.v.x + k11, B.v.y + k12),
                   m3(C.l   + k20, C.v.x + k21, C.v.y + k22));
        acc.y = m3(m3(A.v.x + k00, A.v.y + k01, A.v.z + k02),
                   m3(B.v.x + k10, B.v.y + k11, B.v.z + k12),
                   m3(C.v.x + k20, C.v.y + k21, C.v.z + k22));
        acc.z = m3(m3(A.v.y + k00, A.v.z + k01, A.v.w + k02),
                   m3(B.v.y + k10, B.v.z + k11, B.v.w + k12),
                   m3(C.v.y + k20, C.v.z + k21, C.v.w + k22));
        acc.w = m3(m3(A.v.z + k00, A.v.w + k01, A.r   + k02),
                   m3(B.v.z + k10, B.v.w + k11, B.r   + k12),
                   m3(C.v.z + k20, C.v.w + k21, C.r   + k22));

        *(float4*)(oplane + (size_t)(i0 + o) * W_DIM + j0) = acc;

        A = B; B = C; C = N;
    }
}

extern "C" void kernel_launch(void* const* d_in, const int* in_sizes, int n_in,
                              void* d_out, int out_size, void* d_ws, size_t ws_size,
                              hipStream_t stream) {
    const float* x    = (const float*)d_in[0];
    const float* kern = (const float*)d_in[1];
    float* out        = (float*)d_out;

    const int total = 8 * C_DIM * GS * W4;   // 401,408 threads
    const int block = 256;
    const int grid  = (total + block - 1) / block;
    tropical_conv_kernel<<<grid, block, 0, stream>>>(x, kern, out, total);
}